// Round 3
// baseline (119.722 us; speedup 1.0000x reference)
//
#include <hip/hip_runtime.h>
#include <hip/hip_fp16.h>

#define IN_DIM 16
#define HID 8

typedef int   v4i __attribute__((ext_vector_type(4)));
typedef float v4f __attribute__((ext_vector_type(4)));

__device__ __forceinline__ float fast_tanh(float z) {
    // tanh(z) = 1 - 2/(exp(2z)+1); exp(+inf)->inf => 1, exp(-inf)->0 => -1 (safe limits)
    float e = __expf(2.0f * z);
    return 1.0f - 2.0f * __builtin_amdgcn_rcpf(e + 1.0f);
}

// Per-node precompute, packed fp16: uv[n][0..7]  = u = x[n]·W1[0:16] + b1 ("x[col]" half)
//                                   uv[n][8..15] = v = x[n]·W1[16:32]    ("x[row]" half)
// Total uv = 100K × 32 B = 3.2 MB → fits in one XCD's 4 MB L2.
__global__ __launch_bounds__(256) void node_pre(
    const float* __restrict__ x, const float* __restrict__ W1,
    const float* __restrict__ b1, __half* __restrict__ uv, int n_nodes)
{
    __shared__ float sW[2 * IN_DIM * HID];
    __shared__ float sb[HID];
    int t = threadIdx.x;
    if (t < 2 * IN_DIM * HID) sW[t] = W1[t];
    if (t < HID) sb[t] = b1[t];
    __syncthreads();
    int n = blockIdx.x * 256 + t;
    if (n >= n_nodes) return;

    const float4* xp = (const float4*)(x + (size_t)n * IN_DIM);
    float xr[IN_DIM];
    float4 a;
    a = xp[0]; xr[0]=a.x;  xr[1]=a.y;  xr[2]=a.z;  xr[3]=a.w;
    a = xp[1]; xr[4]=a.x;  xr[5]=a.y;  xr[6]=a.z;  xr[7]=a.w;
    a = xp[2]; xr[8]=a.x;  xr[9]=a.y;  xr[10]=a.z; xr[11]=a.w;
    a = xp[3]; xr[12]=a.x; xr[13]=a.y; xr[14]=a.z; xr[15]=a.w;

    float au[HID], av[HID];
    #pragma unroll
    for (int j = 0; j < HID; j++) { au[j] = sb[j]; av[j] = 0.0f; }
    #pragma unroll
    for (int k = 0; k < IN_DIM; k++) {
        #pragma unroll
        for (int j = 0; j < HID; j++) {
            au[j] = fmaf(xr[k], sW[k * HID + j], au[j]);           // sW wave-uniform -> LDS broadcast
            av[j] = fmaf(xr[k], sW[(IN_DIM + k) * HID + j], av[j]);
        }
    }
    union { __half2 h[4]; float4 f; } pu, pv;
    #pragma unroll
    for (int i = 0; i < 4; i++) {
        pu.h[i] = __floats2half2_rn(au[2*i], au[2*i+1]);
        pv.h[i] = __floats2half2_rn(av[2*i], av[2*i+1]);
    }
    float4* o = (float4*)(uv + (size_t)n * 16);
    o[0] = pu.f;   // u half
    o[1] = pv.f;   // v half
}

__device__ __forceinline__ float edge_eval(float4 uf, float4 vf,
                                           const float* sw2, float sb2)
{
    union { float4 f; __half2 h[4]; } U, V;
    U.f = uf; V.f = vf;
    float s = sb2;
    #pragma unroll
    for (int i = 0; i < 4; i++) {
        float2 a = __half22float2(U.h[i]);
        float2 b = __half22float2(V.h[i]);
        s = fmaf(fast_tanh(a.x + b.x), sw2[2*i],   s);
        s = fmaf(fast_tanh(a.y + b.y), sw2[2*i+1], s);
    }
    return __builtin_amdgcn_rcpf(1.0f + __expf(-s));
}

// 8 edges/thread: 16 independent uv gathers in flight per thread to hide
// the ~200-900 cyc gather latency (round-1 VALUBusy 11% => latency-bound).
__global__ __launch_bounds__(256) void edge_k(
    const int* __restrict__ idx, const __half* __restrict__ uv,
    const float* __restrict__ W2, const float* __restrict__ b2,
    float* __restrict__ out, int n_edges)
{
    __shared__ float sw2[HID];
    __shared__ float sb2;
    int t = threadIdx.x;
    if (t < HID) sw2[t] = W2[t];
    if (t == 0) sb2 = b2[0];
    __syncthreads();
    float lb2 = sb2;

    long e0 = ((long)blockIdx.x * 256 + t) * 8;
    const float4* uvp = (const float4*)uv;  // 16 B granules; node n = granule 2n (u), 2n+1 (v)
    if (e0 + 8 <= n_edges) {
        // streaming (non-temporal) idx loads: don't evict the uv working set from L2
        v4i r0 = __builtin_nontemporal_load((const v4i*)(idx + e0));
        v4i r1 = __builtin_nontemporal_load((const v4i*)(idx + e0 + 4));
        v4i c0 = __builtin_nontemporal_load((const v4i*)(idx + n_edges + e0));
        v4i c1 = __builtin_nontemporal_load((const v4i*)(idx + n_edges + e0 + 4));

        // issue all 16 gathers before any compute
        float4 u0 = uvp[2*(size_t)c0.x],     u1 = uvp[2*(size_t)c0.y];
        float4 u2 = uvp[2*(size_t)c0.z],     u3 = uvp[2*(size_t)c0.w];
        float4 u4 = uvp[2*(size_t)c1.x],     u5 = uvp[2*(size_t)c1.y];
        float4 u6 = uvp[2*(size_t)c1.z],     u7 = uvp[2*(size_t)c1.w];
        float4 w0 = uvp[2*(size_t)r0.x + 1], w1 = uvp[2*(size_t)r0.y + 1];
        float4 w2 = uvp[2*(size_t)r0.z + 1], w3 = uvp[2*(size_t)r0.w + 1];
        float4 w4 = uvp[2*(size_t)r1.x + 1], w5 = uvp[2*(size_t)r1.y + 1];
        float4 w6 = uvp[2*(size_t)r1.z + 1], w7 = uvp[2*(size_t)r1.w + 1];

        v4f o0, o1;
        o0.x = edge_eval(u0, w0, sw2, lb2);
        o0.y = edge_eval(u1, w1, sw2, lb2);
        o0.z = edge_eval(u2, w2, sw2, lb2);
        o0.w = edge_eval(u3, w3, sw2, lb2);
        o1.x = edge_eval(u4, w4, sw2, lb2);
        o1.y = edge_eval(u5, w5, sw2, lb2);
        o1.z = edge_eval(u6, w6, sw2, lb2);
        o1.w = edge_eval(u7, w7, sw2, lb2);
        __builtin_nontemporal_store(o0, (v4f*)(out + e0));
        __builtin_nontemporal_store(o1, (v4f*)(out + e0 + 4));
    } else {
        for (long e = e0; e < n_edges; e++) {
            int row = idx[e];
            int col = idx[n_edges + e];
            out[e] = edge_eval(uvp[2*(size_t)col], uvp[2*(size_t)row + 1], sw2, lb2);
        }
    }
}

extern "C" void kernel_launch(void* const* d_in, const int* in_sizes, int n_in,
                              void* d_out, int out_size, void* d_ws, size_t ws_size,
                              hipStream_t stream) {
    const float* x  = (const float*)d_in[0];
    const int*   idx = (const int*)d_in[1];
    const float* W1 = (const float*)d_in[2];
    const float* b1 = (const float*)d_in[3];
    const float* W2 = (const float*)d_in[4];
    const float* b2 = (const float*)d_in[5];
    float* out = (float*)d_out;

    int n_nodes = in_sizes[0] / IN_DIM;
    int n_edges = in_sizes[1] / 2;

    __half* uv = (__half*)d_ws;   // n_nodes*16 halfs = 3.2 MB (ws must be >= 3.2 MB)

    node_pre<<<(n_nodes + 255) / 256, 256, 0, stream>>>(x, W1, b1, uv, n_nodes);
    int epb = 256 * 8;
    edge_k<<<(n_edges + epb - 1) / epb, 256, 0, stream>>>(idx, uv, W2, b2, out, n_edges);
}

// Round 4
// 117.869 us; speedup vs baseline: 1.0157x; 1.0157x over previous
//
#include <hip/hip_runtime.h>
#include <hip/hip_fp16.h>

#define IN_DIM 16
#define HID 8

typedef int   v4i __attribute__((ext_vector_type(4)));
typedef float v4f __attribute__((ext_vector_type(4)));

__device__ __forceinline__ float fast_tanh(float z) {
    // tanh(z) = 1 - 2/(exp(2z)+1); exp(+inf)->inf => 1, exp(-inf)->0 => -1 (safe limits)
    float e = __expf(2.0f * z);
    return 1.0f - 2.0f * __builtin_amdgcn_rcpf(e + 1.0f);
}

// Per-node precompute, packed fp16: uv[n][0..7]  = u = x[n]·W1[0:16] + b1 ("x[col]" half)
//                                   uv[n][8..15] = v = x[n]·W1[16:32]    ("x[row]" half)
// Total uv = 100K × 32 B = 3.2 MB → resident in each XCD's 4 MB L2.
__global__ __launch_bounds__(256) void node_pre(
    const float* __restrict__ x, const float* __restrict__ W1,
    const float* __restrict__ b1, __half* __restrict__ uv, int n_nodes)
{
    __shared__ float sW[2 * IN_DIM * HID];
    __shared__ float sb[HID];
    int t = threadIdx.x;
    if (t < 2 * IN_DIM * HID) sW[t] = W1[t];
    if (t < HID) sb[t] = b1[t];
    __syncthreads();
    int n = blockIdx.x * 256 + t;
    if (n >= n_nodes) return;

    const float4* xp = (const float4*)(x + (size_t)n * IN_DIM);
    float xr[IN_DIM];
    float4 a;
    a = xp[0]; xr[0]=a.x;  xr[1]=a.y;  xr[2]=a.z;  xr[3]=a.w;
    a = xp[1]; xr[4]=a.x;  xr[5]=a.y;  xr[6]=a.z;  xr[7]=a.w;
    a = xp[2]; xr[8]=a.x;  xr[9]=a.y;  xr[10]=a.z; xr[11]=a.w;
    a = xp[3]; xr[12]=a.x; xr[13]=a.y; xr[14]=a.z; xr[15]=a.w;

    float au[HID], av[HID];
    #pragma unroll
    for (int j = 0; j < HID; j++) { au[j] = sb[j]; av[j] = 0.0f; }
    #pragma unroll
    for (int k = 0; k < IN_DIM; k++) {
        #pragma unroll
        for (int j = 0; j < HID; j++) {
            au[j] = fmaf(xr[k], sW[k * HID + j], au[j]);           // sW wave-uniform -> LDS broadcast
            av[j] = fmaf(xr[k], sW[(IN_DIM + k) * HID + j], av[j]);
        }
    }
    union { __half2 h[4]; float4 f; } pu, pv;
    #pragma unroll
    for (int i = 0; i < 4; i++) {
        pu.h[i] = __floats2half2_rn(au[2*i], au[2*i+1]);
        pv.h[i] = __floats2half2_rn(av[2*i], av[2*i+1]);
    }
    float4* o = (float4*)(uv + (size_t)n * 16);
    o[0] = pu.f;   // u half
    o[1] = pv.f;   // v half
}

// 8 L1-bypassing (sc0) 16 B gathers in one asm block, single trailing waitcnt.
// sc0: L2 returns just the requested beat instead of a 64 B L1 line fill ->
// halves L2 data-port occupancy (the measured ~40 us plateau). No `nt`: uv
// must stay L2-resident. Early-clobber outputs: async writeback must not
// alias still-unconsumed address regs.
__device__ __forceinline__ void gather8_sc0(
    const float4* a0, const float4* a1, const float4* a2, const float4* a3,
    const float4* a4, const float4* a5, const float4* a6, const float4* a7,
    float4& r0, float4& r1, float4& r2, float4& r3,
    float4& r4, float4& r5, float4& r6, float4& r7)
{
    asm volatile(
        "global_load_dwordx4 %0, %8, off sc0\n\t"
        "global_load_dwordx4 %1, %9, off sc0\n\t"
        "global_load_dwordx4 %2, %10, off sc0\n\t"
        "global_load_dwordx4 %3, %11, off sc0\n\t"
        "global_load_dwordx4 %4, %12, off sc0\n\t"
        "global_load_dwordx4 %5, %13, off sc0\n\t"
        "global_load_dwordx4 %6, %14, off sc0\n\t"
        "global_load_dwordx4 %7, %15, off sc0\n\t"
        "s_waitcnt vmcnt(0)"
        : "=&v"(r0), "=&v"(r1), "=&v"(r2), "=&v"(r3),
          "=&v"(r4), "=&v"(r5), "=&v"(r6), "=&v"(r7)
        : "v"(a0), "v"(a1), "v"(a2), "v"(a3),
          "v"(a4), "v"(a5), "v"(a6), "v"(a7)
        : "memory");
}

__device__ __forceinline__ float edge_eval(float4 uf, float4 vf,
                                           const float* sw2, float sb2)
{
    union { float4 f; __half2 h[4]; } U, V;
    U.f = uf; V.f = vf;
    float s = sb2;
    #pragma unroll
    for (int i = 0; i < 4; i++) {
        float2 a = __half22float2(U.h[i]);
        float2 b = __half22float2(V.h[i]);
        s = fmaf(fast_tanh(a.x + b.x), sw2[2*i],   s);
        s = fmaf(fast_tanh(a.y + b.y), sw2[2*i+1], s);
    }
    return __builtin_amdgcn_rcpf(1.0f + __expf(-s));
}

// 4 edges/thread: out[e] = sigmoid( sum_j tanh(u[col][j]+v[row][j]) * W2[j] + b2 )
__global__ __launch_bounds__(256) void edge_k(
    const int* __restrict__ idx, const __half* __restrict__ uv,
    const float* __restrict__ W2, const float* __restrict__ b2,
    float* __restrict__ out, int n_edges)
{
    __shared__ float sw2[HID];
    __shared__ float sb2;
    int t = threadIdx.x;
    if (t < HID) sw2[t] = W2[t];
    if (t == 0) sb2 = b2[0];
    __syncthreads();
    float lb2 = sb2;

    long e0 = ((long)blockIdx.x * 256 + t) * 4;
    const float4* uvp = (const float4*)uv;  // 16 B granules; node n = granule 2n (u), 2n+1 (v)
    if (e0 + 4 <= n_edges) {
        // streaming (non-temporal) idx loads: don't evict the uv working set from L2
        v4i rows = __builtin_nontemporal_load((const v4i*)(idx + e0));
        v4i cols = __builtin_nontemporal_load((const v4i*)(idx + n_edges + e0));

        float4 u0, u1, u2, u3, w0, w1, w2, w3;
        gather8_sc0(uvp + 2*(size_t)cols.x,     uvp + 2*(size_t)cols.y,
                    uvp + 2*(size_t)cols.z,     uvp + 2*(size_t)cols.w,
                    uvp + 2*(size_t)rows.x + 1, uvp + 2*(size_t)rows.y + 1,
                    uvp + 2*(size_t)rows.z + 1, uvp + 2*(size_t)rows.w + 1,
                    u0, u1, u2, u3, w0, w1, w2, w3);

        v4f r;
        r.x = edge_eval(u0, w0, sw2, lb2);
        r.y = edge_eval(u1, w1, sw2, lb2);
        r.z = edge_eval(u2, w2, sw2, lb2);
        r.w = edge_eval(u3, w3, sw2, lb2);
        __builtin_nontemporal_store(r, (v4f*)(out + e0));
    } else {
        for (long e = e0; e < n_edges; e++) {
            int row = idx[e];
            int col = idx[n_edges + e];
            out[e] = edge_eval(uvp[2*(size_t)col], uvp[2*(size_t)row + 1], sw2, lb2);
        }
    }
}

extern "C" void kernel_launch(void* const* d_in, const int* in_sizes, int n_in,
                              void* d_out, int out_size, void* d_ws, size_t ws_size,
                              hipStream_t stream) {
    const float* x  = (const float*)d_in[0];
    const int*   idx = (const int*)d_in[1];
    const float* W1 = (const float*)d_in[2];
    const float* b1 = (const float*)d_in[3];
    const float* W2 = (const float*)d_in[4];
    const float* b2 = (const float*)d_in[5];
    float* out = (float*)d_out;

    int n_nodes = in_sizes[0] / IN_DIM;
    int n_edges = in_sizes[1] / 2;

    __half* uv = (__half*)d_ws;   // n_nodes*16 halfs = 3.2 MB (ws must be >= 3.2 MB)

    node_pre<<<(n_nodes + 255) / 256, 256, 0, stream>>>(x, W1, b1, uv, n_nodes);
    int epb = 256 * 4;
    edge_k<<<(n_edges + epb - 1) / epb, 256, 0, stream>>>(idx, uv, W2, b2, out, n_edges);
}